// Round 7
// baseline (96692.505 us; speedup 1.0000x reference)
//
#include <hip/hip_runtime.h>
#include <math.h>

#define BDIM 256
#define DDIM 2048
constexpr float DT    = 0.1f;
constexpr float TOL   = 0.01f;
constexpr int   NSTEP = 50;      // int(5.0 / 0.1)
constexpr float EPS_  = 1e-8f;

typedef __attribute__((ext_vector_type(8))) short short8;   // 8 bf16 (MFMA A/B frag)
typedef __attribute__((ext_vector_type(4))) float f32x4;    // MFMA C/D frag

__device__ __forceinline__ ushort f2bf(float f) {           // fp32 -> bf16 RNE
    unsigned u = __float_as_uint(f);
    return (ushort)((u + 0x7fffu + ((u >> 16) & 1u)) >> 16);
}
__device__ __forceinline__ float bf2f(ushort h) { return __uint_as_float(((unsigned)h) << 16); }

#define GLOAD_LDS16(g, l) __builtin_amdgcn_global_load_lds( \
    (const __attribute__((address_space(1))) void*)(g),      \
    (__attribute__((address_space(3))) void*)(l), 16, 0, 0)

#define MFMA16(a, b, c) __builtin_amdgcn_mfma_f32_16x16x32_bf16((a), (b), (c), 0, 0, 0)

// ---------------------------------------------------------------------------
// One-time prepack: W -> bf16 hi/lo row-major (NT B operand: W[n][k] k-contig)
// ---------------------------------------------------------------------------
__global__ __launch_bounds__(256)
void prep_w_k(const float* __restrict__ W, ushort* __restrict__ Wh, ushort* __restrict__ Wl)
{
    const size_t i = ((size_t)blockIdx.x * 256 + threadIdx.x) * 4;
    const float4 v = *(const float4*)(W + i);
    ushort4 h, l;
    h.x = f2bf(v.x); l.x = f2bf(v.x - bf2f(h.x));
    h.y = f2bf(v.y); l.y = f2bf(v.y - bf2f(h.y));
    h.z = f2bf(v.z); l.z = f2bf(v.z - bf2f(h.z));
    h.w = f2bf(v.w); l.w = f2bf(v.w - bf2f(h.w));
    *(ushort4*)(Wh + i) = h;
    *(ushort4*)(Wl + i) = l;
}

// One-time prepack: W^T -> bf16 hi/lo (NN B operand: Wt[n][k]=W[k][n] k-contig)
__global__ __launch_bounds__(256)
void prep_wt_k(const float* __restrict__ W, ushort* __restrict__ Wth, ushort* __restrict__ Wtl)
{
    __shared__ float T[64][65];
    const int t = threadIdx.x;
    const int k0 = blockIdx.y * 64, n0 = blockIdx.x * 64;
    const int r = t >> 2, c4 = (t & 3) * 16;
    const float* src = W + (size_t)(k0 + r) * DDIM + n0 + c4;
    #pragma unroll
    for (int j = 0; j < 4; ++j) {
        const float4 v = *(const float4*)(src + j * 4);
        T[r][c4 + j*4 + 0] = v.x; T[r][c4 + j*4 + 1] = v.y;
        T[r][c4 + j*4 + 2] = v.z; T[r][c4 + j*4 + 3] = v.w;
    }
    __syncthreads();
    ushort hb[16], lb[16];
    #pragma unroll
    for (int j = 0; j < 16; ++j) {
        const float v = T[c4 + j][r];
        hb[j] = f2bf(v); lb[j] = f2bf(v - bf2f(hb[j]));
    }
    ushort* oh = Wth + (size_t)(n0 + r) * DDIM + k0 + c4;
    ushort* ol = Wtl + (size_t)(n0 + r) * DDIM + k0 + c4;
    #pragma unroll
    for (int q = 0; q < 4; ++q) {
        *(ushort4*)(oh + q*4) = make_ushort4(hb[q*4], hb[q*4+1], hb[q*4+2], hb[q*4+3]);
        *(ushort4*)(ol + q*4) = make_ushort4(lb[q*4], lb[q*4+1], lb[q*4+2], lb[q*4+3]);
    }
}

// init: x = x0; AB = split(x0); zero csum/maxu/done/flags
__global__ __launch_bounds__(256)
void init6_k(const float* __restrict__ x0, float* __restrict__ x,
             ushort* __restrict__ Ash, ushort* __restrict__ Asl,
             float* __restrict__ csum, unsigned* __restrict__ ctrl)
{
    const size_t i = ((size_t)blockIdx.x * 256 + threadIdx.x) * 4;
    const float4 v = *(const float4*)(x0 + i);
    *(float4*)(x + i) = v;
    ushort4 h, l;
    h.x = f2bf(v.x); l.x = f2bf(v.x - bf2f(h.x));
    h.y = f2bf(v.y); l.y = f2bf(v.y - bf2f(h.y));
    h.z = f2bf(v.z); l.z = f2bf(v.z - bf2f(h.z));
    h.w = f2bf(v.w); l.w = f2bf(v.w - bf2f(h.w));
    *(ushort4*)(Ash + i) = h;
    *(ushort4*)(Asl + i) = l;
    if (blockIdx.x == 0) {
        for (int j = threadIdx.x; j < 1024; j += 256) csum[j] = 0.f;
        if (threadIdx.x < 66) ctrl[threadIdx.x] = 0u;   // maxu, done, flags[64]
    }
}

// ---------------------------------------------------------------------------
// Split-bf16 MFMA GEMM v6b (r6 + staging fix). Tile 128x64, 4 waves
// (wave-tile 64x32: 24 MFMA / 12 ds_read_b128 per BK=32), Ksplit=8
// (K-chunk 256, 8 iters), grid (32,2,8) = 512 blocks -> 2 blocks/CU.
// FIX vs r6: block has 256 threads, so stage() issues SIX 16B DMAs/thread
// (2x Ah rows 0-63/64-127, 2x Al, 1x Bh, 1x Bl) = full 24 KB tile coverage.
// (r6 staged only A rows 0-63 and never staged Bl -> garbage MFMA operands.)
// Row-swizzle (row>>1)&3 has period 8, and row+64 == row (mod 8), so the
// same pre-swizzled source offset serves both A halves.
// Split-K: bz 0..2 chain into pA; bz 3..6 chain into pB; bz 7 waits both,
// adds own acc and runs the fused epilogue. Device-scope acquire/release
// flags, fixed chain order (deterministic), self-reset by the reducer.
// MODE 0: NN  z=A@Wt; epi: h=tanh(z+b), P=split(h(1-h^2)), csum+=h^2
// MODE 1: NT  kv=-cf*z; epi: S=kv, max|kv|, AB=split(x+0.5DT*kv)
// MODE 2: NT  epi: S+=2kv, AB=split(x+0.5DT*kv)
// MODE 3: NT  epi: S+=2kv, AB=split(x+DT*kv)
// MODE 4: NT  epi: x+=DT/6*(S+kv), AB=split(x_new)
// ---------------------------------------------------------------------------
template<int MODE>
__global__ __launch_bounds__(256, 2)
void hop6_mm(const ushort* __restrict__ Ahg, const ushort* __restrict__ Alg,
             const ushort* __restrict__ Bhg, const ushort* __restrict__ Blg,
             const float* __restrict__ bias,
             ushort* __restrict__ Oh, ushort* __restrict__ Ol,
             float* __restrict__ cs_cur, float* __restrict__ cs_next,
             const float* __restrict__ xin, float* __restrict__ xio,
             float* __restrict__ S,
             ushort* __restrict__ Ash, ushort* __restrict__ Asl,
             float cmul, unsigned* __restrict__ maxu, const int* __restrict__ done,
             float* __restrict__ pA, float* __restrict__ pB,
             unsigned* __restrict__ flags)
{
    constexpr bool NN = (MODE == 0);
    if (*done) return;

    // [dbuf][Ah(4096) | Al(4096) | Bh(2048) | Bl(2048)] shorts = 48 KB
    __shared__ __align__(16) ushort lds[2][12288];

    const int t = threadIdx.x, lane = t & 63, wid = t >> 6;
    const int bx = blockIdx.x, by = blockIdx.y, bz = blockIdx.z;
    const int row0 = by * 128, col0 = bx * 64, kb = bz * 256;
    const int wr = wid >> 1, wc = wid & 1;
    const int fr = lane & 15, ch = lane >> 4;

    // ---- staging sources (6 x 16B DMA per thread per iter) ----
    const int sa_row = t >> 2, sa_c = t & 3;                    // A: rows 0..63 (+64)
    const int sa_k = (sa_c ^ ((sa_row >> 1) & 3)) * 8;          // pre-swizzled src
    const ushort* aSrcH0 = Ahg + (size_t)(row0 + sa_row) * DDIM + kb + sa_k;
    const ushort* aSrcH1 = Ahg + (size_t)(row0 + 64 + sa_row) * DDIM + kb + sa_k;
    const ushort* aSrcL0 = Alg + (size_t)(row0 + sa_row) * DDIM + kb + sa_k;
    const ushort* aSrcL1 = Alg + (size_t)(row0 + 64 + sa_row) * DDIM + kb + sa_k;
    const ushort* bSrcH  = Bhg + (size_t)(col0 + sa_row) * DDIM + kb + sa_k;  // B rows 0..63
    const ushort* bSrcL  = Blg + (size_t)(col0 + sa_row) * DDIM + kb + sa_k;

    auto stage = [&](int it, int db) {
        ushort* L = &lds[db][0];
        GLOAD_LDS16(aSrcH0 + it * 32, L + t * 8);
        GLOAD_LDS16(aSrcH1 + it * 32, L + 2048 + t * 8);
        GLOAD_LDS16(aSrcL0 + it * 32, L + 4096 + t * 8);
        GLOAD_LDS16(aSrcL1 + it * 32, L + 6144 + t * 8);
        GLOAD_LDS16(bSrcH  + it * 32, L + 8192 + t * 8);
        GLOAD_LDS16(bSrcL  + it * 32, L + 10240 + t * 8);
    };

    f32x4 acc[4][2];
    #pragma unroll
    for (int m = 0; m < 4; ++m)
        #pragma unroll
        for (int n = 0; n < 2; ++n)
            #pragma unroll
            for (int j = 0; j < 4; ++j) acc[m][n][j] = 0.f;

    stage(0, 0);
    __syncthreads();

    for (int it = 0; it < 8; ++it) {
        const int db = it & 1;
        if (it < 7) stage(it + 1, db ^ 1);
        const ushort* L = &lds[db][0];
        short8 ah[4], al[4], bh[2], bl[2];
        #pragma unroll
        for (int m = 0; m < 4; ++m) {
            const int ar = wr * 64 + m * 16 + fr;
            const int off = ar * 32 + ((ch ^ ((ar >> 1) & 3)) * 8);
            ah[m] = *(const short8*)&L[off];
            al[m] = *(const short8*)&L[4096 + off];
        }
        #pragma unroll
        for (int n = 0; n < 2; ++n) {
            const int br = wc * 32 + n * 16 + fr;
            const int off = br * 32 + ((ch ^ ((br >> 1) & 3)) * 8);
            bh[n] = *(const short8*)&L[8192 + off];
            bl[n] = *(const short8*)&L[10240 + off];
        }
        #pragma unroll
        for (int m = 0; m < 4; ++m)
            #pragma unroll
            for (int n = 0; n < 2; ++n) {
                acc[m][n] = MFMA16(ah[m], bh[n], acc[m][n]);
                acc[m][n] = MFMA16(ah[m], bl[n], acc[m][n]);
                acc[m][n] = MFMA16(al[m], bh[n], acc[m][n]);
            }
        __syncthreads();
    }

    // ---- split-K chain reduction ----
    unsigned* flg = flags + (bx + 32 * by);

    if (bz != 7) {
        unsigned need = 0u;
        if (bz == 1 || bz == 2 || bz == 4 || bz == 5 || bz == 6) need = 1u << (bz - 1);
        float* pb = (bz <= 2) ? pA : pB;
        if (need) {
            if (t == 0)
                while ((__hip_atomic_load(flg, __ATOMIC_ACQUIRE, __HIP_MEMORY_SCOPE_AGENT) & need) == 0u)
                    __builtin_amdgcn_s_sleep(2);
            __syncthreads();
            __threadfence();
        }
        const bool first = (bz == 0 || bz == 3);
        #pragma unroll
        for (int m = 0; m < 4; ++m)
            #pragma unroll
            for (int n = 0; n < 2; ++n)
                #pragma unroll
                for (int j = 0; j < 4; ++j) {
                    const int row = row0 + wr * 64 + m * 16 + ch * 4 + j;
                    const int col = col0 + wc * 32 + n * 16 + fr;
                    const size_t idx = (size_t)row * DDIM + col;
                    if (first) pb[idx] = acc[m][n][j];
                    else       pb[idx] += acc[m][n][j];
                }
        __threadfence();
        __syncthreads();
        if (t == 0) __hip_atomic_fetch_or(flg, 1u << bz, __ATOMIC_RELEASE, __HIP_MEMORY_SCOPE_AGENT);
        return;
    }

    // ---- reducer (bz==7): wait for both chains, combine, fused epilogue ----
    if (t == 0)
        while ((__hip_atomic_load(flg, __ATOMIC_ACQUIRE, __HIP_MEMORY_SCOPE_AGENT) & 0x44u) != 0x44u)
            __builtin_amdgcn_s_sleep(2);
    __syncthreads();
    __threadfence();

    if constexpr (NN) {
        #pragma unroll
        for (int m = 0; m < 4; ++m)
            #pragma unroll
            for (int j = 0; j < 4; ++j) {
                const int row = row0 + wr * 64 + m * 16 + ch * 4 + j;
                float s2 = 0.f;
                #pragma unroll
                for (int n = 0; n < 2; ++n) {
                    const int col = col0 + wc * 32 + n * 16 + fr;
                    const size_t idx = (size_t)row * DDIM + col;
                    const float z = acc[m][n][j] + pA[idx] + pB[idx];
                    const float h = tanhf(z + bias[col]);
                    s2 += h * h;
                    const float p = h * (1.f - h * h);
                    const ushort ph = f2bf(p);
                    Oh[idx] = ph; Ol[idx] = f2bf(p - bf2f(ph));
                }
                s2 += __shfl_xor(s2, 1); s2 += __shfl_xor(s2, 2);
                s2 += __shfl_xor(s2, 4); s2 += __shfl_xor(s2, 8);
                if (fr == 0) atomicAdd(&cs_cur[row], s2);
            }
    } else {
        float mx = 0.f;
        #pragma unroll
        for (int m = 0; m < 4; ++m)
            #pragma unroll
            for (int j = 0; j < 4; ++j) {
                const int row = row0 + wr * 64 + m * 16 + ch * 4 + j;
                const float cf = 5.0f / (sqrtf(cs_cur[row]) + EPS_);
                #pragma unroll
                for (int n = 0; n < 2; ++n) {
                    const int col = col0 + wc * 32 + n * 16 + fr;
                    const size_t idx = (size_t)row * DDIM + col;
                    const float kv = -cf * (acc[m][n][j] + pA[idx] + pB[idx]);
                    if constexpr (MODE == 1) { S[idx] = kv; mx = fmaxf(mx, fabsf(kv)); }
                    if constexpr (MODE == 2 || MODE == 3) { S[idx] += 2.f * kv; }
                    if constexpr (MODE <= 3) {
                        const float a = xin[idx] + cmul * kv;
                        const ushort ahh = f2bf(a);
                        Ash[idx] = ahh; Asl[idx] = f2bf(a - bf2f(ahh));
                    } else {
                        const float xn = xin[idx] + (DT / 6.0f) * (S[idx] + kv);
                        xio[idx] = xn;
                        const ushort ahh = f2bf(xn);
                        Ash[idx] = ahh; Asl[idx] = f2bf(xn - bf2f(ahh));
                    }
                }
            }
        if constexpr (MODE == 1) {
            #pragma unroll
            for (int msk = 1; msk <= 32; msk <<= 1) mx = fmaxf(mx, __shfl_xor(mx, msk));
            if (lane == 0) atomicMax(maxu, __float_as_uint(mx));
        }
        if (bx == 0 && by == 0) cs_next[t] = 0.f;
    }

    if (t == 0) __hip_atomic_store(flg, 0u, __ATOMIC_RELAXED, __HIP_MEMORY_SCOPE_AGENT);
}

__global__ void finalize_k(unsigned* __restrict__ maxu, int* __restrict__ done)
{
    if (!*done) {
        if (__uint_as_float(*maxu) < TOL) *done = 1;
    }
    *maxu = 0u;
}

__global__ __launch_bounds__(256)
void copy_k(const float* __restrict__ src, float* __restrict__ dst)
{
    const size_t i = ((size_t)blockIdx.x * 256 + threadIdx.x) * 4;
    *(float4*)&dst[i] = *(const float4*)&src[i];
}

// ===========================================================================
extern "C" void kernel_launch(void* const* d_in, const int* in_sizes, int n_in,
                              void* d_out, int out_size, void* d_ws, size_t ws_size,
                              hipStream_t stream)
{
    const float* x0   = (const float*)d_in[0];
    const float* W    = (const float*)d_in[1];
    const float* bias = (const float*)d_in[2];
    float* out = (float*)d_out;

    const size_t NE = (size_t)BDIM * DDIM;   // 524288
    const size_t M4 = (size_t)DDIM * DDIM;   // 4194304

    // ws layout: 44,044,608 B <= proven ws (r2-r5 ran the 44.0 MB-gated path)
    float* ws = (float*)d_ws;
    float* x    = ws;                        // NE
    float* S    = ws + NE;                   // NE
    float* pA   = ws + 2 * NE;               // NE (split-K partial chain A)
    float* csum = ws + 3 * NE;               // 1024 (4 stage buffers x 256)
    unsigned* ctrl = (unsigned*)(csum + 1024);
    unsigned* maxu = ctrl;                   // [0]
    int*      done = (int*)(ctrl + 1);       // [1]
    unsigned* flags = ctrl + 2;              // [2..65]
    ushort* us = (ushort*)(ws + 3 * NE + 1104);   // 16B-aligned
    ushort* ABh = us;                // NE: A-side (x + c*k) hi
    ushort* ABl = us + NE;           // NE
    ushort* Ph  = us + 2 * NE;       // NE: p = h(1-h^2) hi
    ushort* Pl  = us + 3 * NE;       // NE
    ushort* Wth = us + 4 * NE;       // M4: W^T hi (NN B)
    ushort* Wtl = Wth + M4;          // M4
    ushort* Wh  = Wth + 2 * M4;      // M4: W hi (NT B)
    ushort* Wl  = Wth + 3 * M4;      // M4
    float* pB = out;                 // d_out doubles as partial chain B scratch

    prep_w_k <<<4096, 256, 0, stream>>>(W, Wh, Wl);
    prep_wt_k<<<dim3(32, 32), 256, 0, stream>>>(W, Wth, Wtl);
    init6_k  <<<512, 256, 0, stream>>>(x0, x, ABh, ABl, csum, ctrl);

    const dim3 gG(32, 2, 8);                 // 512 blocks, 2/CU
    float* cs0 = csum, *cs1 = csum + 256, *cs2 = csum + 512, *cs3 = csum + 768;

    for (int s = 0; s < NSTEP; ++s) {
        // k1 = pvf(x): NN then NT(mode1) + stop condition
        hop6_mm<0><<<gG, 256, 0, stream>>>(ABh, ABl, Wth, Wtl, bias, Ph, Pl,
                                           cs0, nullptr, nullptr, nullptr, nullptr,
                                           nullptr, nullptr, 0.f, nullptr, done, pA, pB, flags);
        hop6_mm<1><<<gG, 256, 0, stream>>>(Ph, Pl, Wh, Wl, nullptr, nullptr, nullptr,
                                           cs0, cs1, x, nullptr, S,
                                           ABh, ABl, 0.5f * DT, maxu, done, pA, pB, flags);
        finalize_k<<<1, 1, 0, stream>>>(maxu, done);
        // k2
        hop6_mm<0><<<gG, 256, 0, stream>>>(ABh, ABl, Wth, Wtl, bias, Ph, Pl,
                                           cs1, nullptr, nullptr, nullptr, nullptr,
                                           nullptr, nullptr, 0.f, nullptr, done, pA, pB, flags);
        hop6_mm<2><<<gG, 256, 0, stream>>>(Ph, Pl, Wh, Wl, nullptr, nullptr, nullptr,
                                           cs1, cs2, x, nullptr, S,
                                           ABh, ABl, 0.5f * DT, nullptr, done, pA, pB, flags);
        // k3
        hop6_mm<0><<<gG, 256, 0, stream>>>(ABh, ABl, Wth, Wtl, bias, Ph, Pl,
                                           cs2, nullptr, nullptr, nullptr, nullptr,
                                           nullptr, nullptr, 0.f, nullptr, done, pA, pB, flags);
        hop6_mm<3><<<gG, 256, 0, stream>>>(Ph, Pl, Wh, Wl, nullptr, nullptr, nullptr,
                                           cs2, cs3, x, nullptr, S,
                                           ABh, ABl, DT, nullptr, done, pA, pB, flags);
        // k4 + RK4 x-update fused
        hop6_mm<0><<<gG, 256, 0, stream>>>(ABh, ABl, Wth, Wtl, bias, Ph, Pl,
                                           cs3, nullptr, nullptr, nullptr, nullptr,
                                           nullptr, nullptr, 0.f, nullptr, done, pA, pB, flags);
        hop6_mm<4><<<gG, 256, 0, stream>>>(Ph, Pl, Wh, Wl, nullptr, nullptr, nullptr,
                                           cs3, cs0, x, x, S,
                                           ABh, ABl, 0.f, nullptr, done, pA, pB, flags);
    }

    copy_k<<<512, 256, 0, stream>>>(x, out);
}

// Round 8
// 10739.572 us; speedup vs baseline: 9.0034x; 9.0034x over previous
//
#include <hip/hip_runtime.h>
#include <math.h>

#define BDIM 256
#define DDIM 2048
constexpr float DT    = 0.1f;
constexpr float TOL   = 0.01f;
constexpr int   NSTEP = 50;      // int(5.0 / 0.1)
constexpr float EPS_  = 1e-8f;

typedef __attribute__((ext_vector_type(8))) short short8;   // 8 bf16 (MFMA A/B frag)
typedef __attribute__((ext_vector_type(4))) float f32x4;    // MFMA C/D frag

__device__ __forceinline__ ushort f2bf(float f) {           // fp32 -> bf16 RNE
    unsigned u = __float_as_uint(f);
    return (ushort)((u + 0x7fffu + ((u >> 16) & 1u)) >> 16);
}
__device__ __forceinline__ float bf2f(ushort h) { return __uint_as_float(((unsigned)h) << 16); }

#define GLOAD_LDS16(g, l) __builtin_amdgcn_global_load_lds( \
    (const __attribute__((address_space(1))) void*)(g),      \
    (__attribute__((address_space(3))) void*)(l), 16, 0, 0)

#define MFMA16(a, b, c) __builtin_amdgcn_mfma_f32_16x16x32_bf16((a), (b), (c), 0, 0, 0)

// ---------------------------------------------------------------------------
// One-time prepack: W -> bf16 hi/lo row-major (NT B operand: W[n][k] k-contig)
// ---------------------------------------------------------------------------
__global__ __launch_bounds__(256)
void prep_w_k(const float* __restrict__ W, ushort* __restrict__ Wh, ushort* __restrict__ Wl)
{
    const size_t i = ((size_t)blockIdx.x * 256 + threadIdx.x) * 4;
    const float4 v = *(const float4*)(W + i);
    ushort4 h, l;
    h.x = f2bf(v.x); l.x = f2bf(v.x - bf2f(h.x));
    h.y = f2bf(v.y); l.y = f2bf(v.y - bf2f(h.y));
    h.z = f2bf(v.z); l.z = f2bf(v.z - bf2f(h.z));
    h.w = f2bf(v.w); l.w = f2bf(v.w - bf2f(h.w));
    *(ushort4*)(Wh + i) = h;
    *(ushort4*)(Wl + i) = l;
}

// One-time prepack: W^T -> bf16 hi/lo (NN B operand: Wt[n][k]=W[k][n] k-contig)
__global__ __launch_bounds__(256)
void prep_wt_k(const float* __restrict__ W, ushort* __restrict__ Wth, ushort* __restrict__ Wtl)
{
    __shared__ float T[64][65];
    const int t = threadIdx.x;
    const int k0 = blockIdx.y * 64, n0 = blockIdx.x * 64;
    const int r = t >> 2, c4 = (t & 3) * 16;
    const float* src = W + (size_t)(k0 + r) * DDIM + n0 + c4;
    #pragma unroll
    for (int j = 0; j < 4; ++j) {
        const float4 v = *(const float4*)(src + j * 4);
        T[r][c4 + j*4 + 0] = v.x; T[r][c4 + j*4 + 1] = v.y;
        T[r][c4 + j*4 + 2] = v.z; T[r][c4 + j*4 + 3] = v.w;
    }
    __syncthreads();
    ushort hb[16], lb[16];
    #pragma unroll
    for (int j = 0; j < 16; ++j) {
        const float v = T[c4 + j][r];
        hb[j] = f2bf(v); lb[j] = f2bf(v - bf2f(hb[j]));
    }
    ushort* oh = Wth + (size_t)(n0 + r) * DDIM + k0 + c4;
    ushort* ol = Wtl + (size_t)(n0 + r) * DDIM + k0 + c4;
    #pragma unroll
    for (int q = 0; q < 4; ++q) {
        *(ushort4*)(oh + q*4) = make_ushort4(hb[q*4], hb[q*4+1], hb[q*4+2], hb[q*4+3]);
        *(ushort4*)(ol + q*4) = make_ushort4(lb[q*4], lb[q*4+1], lb[q*4+2], lb[q*4+3]);
    }
}

// init: x = x0; AB = split(x0); zero csum/maxu/done
__global__ __launch_bounds__(256)
void init3_k(const float* __restrict__ x0, float* __restrict__ x,
             ushort* __restrict__ Ash, ushort* __restrict__ Asl,
             float* __restrict__ csum, unsigned* __restrict__ maxu, int* __restrict__ done)
{
    const size_t i = ((size_t)blockIdx.x * 256 + threadIdx.x) * 4;
    const float4 v = *(const float4*)(x0 + i);
    *(float4*)(x + i) = v;
    ushort4 h, l;
    h.x = f2bf(v.x); l.x = f2bf(v.x - bf2f(h.x));
    h.y = f2bf(v.y); l.y = f2bf(v.y - bf2f(h.y));
    h.z = f2bf(v.z); l.z = f2bf(v.z - bf2f(h.z));
    h.w = f2bf(v.w); l.w = f2bf(v.w - bf2f(h.w));
    *(ushort4*)(Ash + i) = h;
    *(ushort4*)(Asl + i) = l;
    if (blockIdx.x == 0) {
        for (int j = threadIdx.x; j < 1024; j += 256) csum[j] = 0.f;
        if (threadIdx.x == 0) { *maxu = 0u; *done = 0; }
    }
}

// ---------------------------------------------------------------------------
// Split-bf16 MFMA GEMM v8 = r4 structure + BK=128 (16 iters, half the drains)
// + dual accumulator chains. Tile 32x32, 4 waves (16x16 quadrant each),
// grid (64,8)=512 blocks -> 2 blocks/CU (64 KB LDS). Plain 2-phase loop:
// stage(it+1) -> ds_read+MFMA(it) -> __syncthreads (proven r4 schedule).
// XOR swizzle (rule 21): 16B chunk c ^= (row&7); pre-swizzled DMA source +
// swizzled frag read (involution).
// MODE 0: NN  z=A@Wt; epi: h=tanh(z+b), P=split(h(1-h^2)), csum+=h^2
// MODE 5: NN + folded finalize (block00: done|=max|k1|<TOL, maxu=0)
// MODE 1: NT  kv=-cf*z; epi: S=kv, max|kv|, AB=split(x+0.5DT*kv)
// MODE 2: NT  epi: S+=2kv, AB=split(x+0.5DT*kv)
// MODE 3: NT  epi: S+=2kv, AB=split(x+DT*kv)
// MODE 4: NT  epi: x+=DT/6*(S+kv), AB=split(x_new)
// NT modes zero cs_next (block 0,0) at kernel end.
// ---------------------------------------------------------------------------
template<int MODE>
__global__ __launch_bounds__(256, 2)
void hop8_mm(const ushort* __restrict__ Ahg, const ushort* __restrict__ Alg,
             const ushort* __restrict__ Bhg, const ushort* __restrict__ Blg,
             const float* __restrict__ bias,
             ushort* __restrict__ Oh, ushort* __restrict__ Ol,
             float* __restrict__ cs_cur, float* __restrict__ cs_next,
             const float* __restrict__ xin, float* __restrict__ xio,
             float* __restrict__ S,
             ushort* __restrict__ Ash, ushort* __restrict__ Asl,
             float cmul, unsigned* __restrict__ maxu, int* __restrict__ done)
{
    constexpr bool NN  = (MODE == 0 || MODE == 5);
    constexpr bool FIN = (MODE == 5);

    if constexpr (FIN) {
        // folded stop-condition update (was finalize_k). Race with other
        // blocks' done-read is benign: once done, their outputs are unused.
        if (blockIdx.x == 0 && blockIdx.y == 0 && threadIdx.x == 0) {
            if (!*done && __uint_as_float(*maxu) < TOL) *done = 1;
            *maxu = 0u;
        }
    }
    if (*done) return;

    // [dbuf][Ah|Al|Bh|Bl][32 rows][128 k-shorts] = 64 KB
    __shared__ __align__(16) ushort lds[2][16384];

    const int t = threadIdx.x, lane = t & 63, wid = t >> 6;
    const int wr = wid >> 1, wc = wid & 1;
    const int row0 = blockIdx.y * 32, col0 = blockIdx.x * 32;
    const int fr = lane & 15, cq = lane >> 4;

    // ---- staging: wave wid owns species wid (0=Ah,1=Al,2=Bh,3=Bl) ----
    // per iter: 8 DMA x 1KB per wave (rows 4j..4j+3, 16B chunks 0..15).
    const ushort* sp_src = (wid == 0) ? Ahg : (wid == 1) ? Alg : (wid == 2) ? Bhg : Blg;
    const int sp_base = (wid < 2) ? row0 : col0;
    const int srow4 = lane >> 4, schk = lane & 15;

    auto stage = [&](int it, int db) {
        ushort* L = &lds[db][wid * 4096];
        #pragma unroll
        for (int j = 0; j < 8; ++j) {
            const int r = 4 * j + srow4;
            const ushort* g = sp_src + (size_t)(sp_base + r) * DDIM + it * 128
                              + ((schk ^ (r & 7)) * 8);           // pre-swizzled src
            GLOAD_LDS16(g, L + j * 512 + lane * 8);
        }
    };

    f32x4 acc_e = {0.f, 0.f, 0.f, 0.f};
    f32x4 acc_o = {0.f, 0.f, 0.f, 0.f};

    const int arow = wr * 16 + fr, brow = wc * 16 + fr;
    const int aoffb = arow * 128, boffb = brow * 128;
    const int sa = arow & 7, sb = brow & 7;

    stage(0, 0);
    __syncthreads();

    for (int it = 0; it < 16; ++it) {
        const int db = it & 1;
        if (it < 15) stage(it + 1, db ^ 1);    // prefetch hides under compute
        const ushort* L = &lds[db][0];
        #pragma unroll
        for (int ks = 0; ks < 4; ++ks) {
            const int ca = ((ks * 4 + cq) ^ sa) * 8;
            const int cb = ((ks * 4 + cq) ^ sb) * 8;
            const short8 ah = *(const short8*)&L[        aoffb + ca];
            const short8 al = *(const short8*)&L[ 4096 + aoffb + ca];
            const short8 bh = *(const short8*)&L[ 8192 + boffb + cb];
            const short8 bl = *(const short8*)&L[12288 + boffb + cb];
            if (ks & 1) {
                acc_o = MFMA16(ah, bh, acc_o);
                acc_o = MFMA16(ah, bl, acc_o);
                acc_o = MFMA16(al, bh, acc_o);
            } else {
                acc_e = MFMA16(ah, bh, acc_e);
                acc_e = MFMA16(ah, bl, acc_e);
                acc_e = MFMA16(al, bh, acc_e);
            }
        }
        __syncthreads();
    }

    f32x4 acc;
    #pragma unroll
    for (int j = 0; j < 4; ++j) acc[j] = acc_e[j] + acc_o[j];

    // ---- epilogue. C/D: col=lane&15, row=(lane>>4)*4+j ----
    const int r0 = row0 + wr * 16 + cq * 4;
    const int c0 = col0 + wc * 16 + fr;

    if constexpr (NN) {
        const float b0 = bias[c0];
        float s2[4];
        #pragma unroll
        for (int j = 0; j < 4; ++j) {
            const float h0 = tanhf(acc[j] + b0);
            s2[j] = h0 * h0;
            const float p0 = h0 * (1.f - h0 * h0);
            const size_t i0 = (size_t)(r0 + j) * DDIM + c0;
            const ushort ph = f2bf(p0);
            Oh[i0] = ph; Ol[i0] = f2bf(p0 - bf2f(ph));
        }
        #pragma unroll
        for (int m = 1; m <= 8; m <<= 1)
            #pragma unroll
            for (int j = 0; j < 4; ++j) s2[j] += __shfl_xor(s2[j], m);
        if (fr == 0) {
            #pragma unroll
            for (int j = 0; j < 4; ++j) atomicAdd(&cs_cur[r0 + j], s2[j]);
        }
    } else {
        float mx = 0.f;
        #pragma unroll
        for (int j = 0; j < 4; ++j) {
            const float cf = 5.0f / (sqrtf(cs_cur[r0 + j]) + EPS_);
            const float kv = -cf * acc[j];
            const size_t idx = (size_t)(r0 + j) * DDIM + c0;
            if constexpr (MODE == 1) { S[idx] = kv; mx = fmaxf(mx, fabsf(kv)); }
            if constexpr (MODE == 2 || MODE == 3) { S[idx] += 2.f * kv; }
            if constexpr (MODE <= 3) {
                const float a = xin[idx] + cmul * kv;
                const ushort ahh = f2bf(a);
                Ash[idx] = ahh; Asl[idx] = f2bf(a - bf2f(ahh));
            } else {
                const float xn = xin[idx] + (DT / 6.0f) * (S[idx] + kv);
                xio[idx] = xn;
                const ushort ahh = f2bf(xn);
                Ash[idx] = ahh; Asl[idx] = f2bf(xn - bf2f(ahh));
            }
        }
        if constexpr (MODE == 1) {
            #pragma unroll
            for (int m = 1; m <= 32; m <<= 1) mx = fmaxf(mx, __shfl_xor(mx, m));
            if (lane == 0) atomicMax(maxu, __float_as_uint(mx));
        }
    }

    if (!NN && blockIdx.x == 0 && blockIdx.y == 0) cs_next[t] = 0.f;
}

__global__ __launch_bounds__(256)
void copy_k(const float* __restrict__ src, float* __restrict__ dst)
{
    const size_t i = ((size_t)blockIdx.x * 256 + threadIdx.x) * 4;
    *(float4*)&dst[i] = *(const float4*)&src[i];
}

// ===========================================================================
extern "C" void kernel_launch(void* const* d_in, const int* in_sizes, int n_in,
                              void* d_out, int out_size, void* d_ws, size_t ws_size,
                              hipStream_t stream)
{
    const float* x0   = (const float*)d_in[0];
    const float* W    = (const float*)d_in[1];
    const float* bias = (const float*)d_in[2];
    float* out = (float*)d_out;

    const size_t NE = (size_t)BDIM * DDIM;   // 524288
    const size_t M4 = (size_t)DDIM * DDIM;   // 4194304

    // ws layout (~42 MB; fits the proven >=44.0 MB workspace)
    float* ws = (float*)d_ws;
    float* x    = ws;                        // NE
    float* S    = ws + NE;                   // NE
    float* csum = ws + 2 * NE;               // 1024 (4 stage buffers x 256)
    unsigned* maxu = (unsigned*)(csum + 1024);
    int*      done = (int*)(maxu + 1);
    ushort* us = (ushort*)(ws + 2 * NE + 1032);   // 16B-aligned
    ushort* ABh = us;                // NE: A-side (x + c*k) hi
    ushort* ABl = us + NE;           // NE
    ushort* Ph  = us + 2 * NE;       // NE: p = h(1-h^2) hi
    ushort* Pl  = us + 3 * NE;       // NE
    ushort* Wth = us + 4 * NE;       // M4: W^T hi (NN B)
    ushort* Wtl = Wth + M4;          // M4
    ushort* Wh  = Wth + 2 * M4;      // M4: W hi (NT B)
    ushort* Wl  = Wth + 3 * M4;      // M4

    prep_w_k <<<4096, 256, 0, stream>>>(W, Wh, Wl);
    prep_wt_k<<<dim3(32, 32), 256, 0, stream>>>(W, Wth, Wtl);
    init3_k  <<<512, 256, 0, stream>>>(x0, x, ABh, ABl, csum, maxu, done);

    const dim3 gG(DDIM / 32, BDIM / 32);     // (64, 8) = 512 blocks, 2/CU
    float* cs0 = csum, *cs1 = csum + 256, *cs2 = csum + 512, *cs3 = csum + 768;

    for (int s = 0; s < NSTEP; ++s) {
        // k1 = pvf(x): NN then NT(mode1, sets maxu)
        hop8_mm<0><<<gG, 256, 0, stream>>>(ABh, ABl, Wth, Wtl, bias, Ph, Pl,
                                           cs0, nullptr, nullptr, nullptr, nullptr,
                                           nullptr, nullptr, 0.f, maxu, done);
        hop8_mm<1><<<gG, 256, 0, stream>>>(Ph, Pl, Wh, Wl, nullptr, nullptr, nullptr,
                                           cs0, cs1, x, nullptr, S,
                                           ABh, ABl, 0.5f * DT, maxu, done);
        // k2 (NN carries the folded finalize)
        hop8_mm<5><<<gG, 256, 0, stream>>>(ABh, ABl, Wth, Wtl, bias, Ph, Pl,
                                           cs1, nullptr, nullptr, nullptr, nullptr,
                                           nullptr, nullptr, 0.f, maxu, done);
        hop8_mm<2><<<gG, 256, 0, stream>>>(Ph, Pl, Wh, Wl, nullptr, nullptr, nullptr,
                                           cs1, cs2, x, nullptr, S,
                                           ABh, ABl, 0.5f * DT, maxu, done);
        // k3
        hop8_mm<0><<<gG, 256, 0, stream>>>(ABh, ABl, Wth, Wtl, bias, Ph, Pl,
                                           cs2, nullptr, nullptr, nullptr, nullptr,
                                           nullptr, nullptr, 0.f, maxu, done);
        hop8_mm<3><<<gG, 256, 0, stream>>>(Ph, Pl, Wh, Wl, nullptr, nullptr, nullptr,
                                           cs2, cs3, x, nullptr, S,
                                           ABh, ABl, DT, maxu, done);
        // k4 + RK4 x-update fused
        hop8_mm<0><<<gG, 256, 0, stream>>>(ABh, ABl, Wth, Wtl, bias, Ph, Pl,
                                           cs3, nullptr, nullptr, nullptr, nullptr,
                                           nullptr, nullptr, 0.f, maxu, done);
        hop8_mm<4><<<gG, 256, 0, stream>>>(Ph, Pl, Wh, Wl, nullptr, nullptr, nullptr,
                                           cs3, cs0, x, x, S,
                                           ABh, ABl, 0.f, maxu, done);
    }

    copy_k<<<512, 256, 0, stream>>>(x, out);
}

// Round 9
// 10423.934 us; speedup vs baseline: 9.2760x; 1.0303x over previous
//
#include <hip/hip_runtime.h>
#include <math.h>

#define BDIM 256
#define DDIM 2048
constexpr float DT    = 0.1f;
constexpr float TOL   = 0.01f;
constexpr int   NSTEP = 50;      // int(5.0 / 0.1)
constexpr float EPS_  = 1e-8f;

typedef __attribute__((ext_vector_type(8))) short short8;   // 8 bf16 (MFMA A/B frag)
typedef __attribute__((ext_vector_type(4))) float f32x4;    // MFMA C/D frag

__device__ __forceinline__ ushort f2bf(float f) {           // fp32 -> bf16 RNE
    unsigned u = __float_as_uint(f);
    return (ushort)((u + 0x7fffu + ((u >> 16) & 1u)) >> 16);
}
__device__ __forceinline__ float bf2f(ushort h) { return __uint_as_float(((unsigned)h) << 16); }

#define GLOAD_LDS16(g, l) __builtin_amdgcn_global_load_lds( \
    (const __attribute__((address_space(1))) void*)(g),      \
    (__attribute__((address_space(3))) void*)(l), 16, 0, 0)

#define MFMA16(a, b, c) __builtin_amdgcn_mfma_f32_16x16x32_bf16((a), (b), (c), 0, 0, 0)

// ---------------------------------------------------------------------------
// One-time prepack: W -> bf16 hi/lo row-major (NT B operand: W[n][k] k-contig)
// ---------------------------------------------------------------------------
__global__ __launch_bounds__(256)
void prep_w_k(const float* __restrict__ W, ushort* __restrict__ Wh, ushort* __restrict__ Wl)
{
    const size_t i = ((size_t)blockIdx.x * 256 + threadIdx.x) * 4;
    const float4 v = *(const float4*)(W + i);
    ushort4 h, l;
    h.x = f2bf(v.x); l.x = f2bf(v.x - bf2f(h.x));
    h.y = f2bf(v.y); l.y = f2bf(v.y - bf2f(h.y));
    h.z = f2bf(v.z); l.z = f2bf(v.z - bf2f(h.z));
    h.w = f2bf(v.w); l.w = f2bf(v.w - bf2f(h.w));
    *(ushort4*)(Wh + i) = h;
    *(ushort4*)(Wl + i) = l;
}

// One-time prepack: W^T -> bf16 hi/lo (NN B operand: Wt[n][k]=W[k][n] k-contig)
__global__ __launch_bounds__(256)
void prep_wt_k(const float* __restrict__ W, ushort* __restrict__ Wth, ushort* __restrict__ Wtl)
{
    __shared__ float T[64][65];
    const int t = threadIdx.x;
    const int k0 = blockIdx.y * 64, n0 = blockIdx.x * 64;
    const int r = t >> 2, c4 = (t & 3) * 16;
    const float* src = W + (size_t)(k0 + r) * DDIM + n0 + c4;
    #pragma unroll
    for (int j = 0; j < 4; ++j) {
        const float4 v = *(const float4*)(src + j * 4);
        T[r][c4 + j*4 + 0] = v.x; T[r][c4 + j*4 + 1] = v.y;
        T[r][c4 + j*4 + 2] = v.z; T[r][c4 + j*4 + 3] = v.w;
    }
    __syncthreads();
    ushort hb[16], lb[16];
    #pragma unroll
    for (int j = 0; j < 16; ++j) {
        const float v = T[c4 + j][r];
        hb[j] = f2bf(v); lb[j] = f2bf(v - bf2f(hb[j]));
    }
    ushort* oh = Wth + (size_t)(n0 + r) * DDIM + k0 + c4;
    ushort* ol = Wtl + (size_t)(n0 + r) * DDIM + k0 + c4;
    #pragma unroll
    for (int q = 0; q < 4; ++q) {
        *(ushort4*)(oh + q*4) = make_ushort4(hb[q*4], hb[q*4+1], hb[q*4+2], hb[q*4+3]);
        *(ushort4*)(ol + q*4) = make_ushort4(lb[q*4], lb[q*4+1], lb[q*4+2], lb[q*4+3]);
    }
}

// init: x = x0; AB = split(x0); zero csum/maxu/done
__global__ __launch_bounds__(256)
void init3_k(const float* __restrict__ x0, float* __restrict__ x,
             ushort* __restrict__ Ash, ushort* __restrict__ Asl,
             float* __restrict__ csum, unsigned* __restrict__ maxu, int* __restrict__ done)
{
    const size_t i = ((size_t)blockIdx.x * 256 + threadIdx.x) * 4;
    const float4 v = *(const float4*)(x0 + i);
    *(float4*)(x + i) = v;
    ushort4 h, l;
    h.x = f2bf(v.x); l.x = f2bf(v.x - bf2f(h.x));
    h.y = f2bf(v.y); l.y = f2bf(v.y - bf2f(h.y));
    h.z = f2bf(v.z); l.z = f2bf(v.z - bf2f(h.z));
    h.w = f2bf(v.w); l.w = f2bf(v.w - bf2f(h.w));
    *(ushort4*)(Ash + i) = h;
    *(ushort4*)(Asl + i) = l;
    if (blockIdx.x == 0) {
        for (int j = threadIdx.x; j < 1024; j += 256) csum[j] = 0.f;
        if (threadIdx.x == 0) { *maxu = 0u; *done = 0; }
    }
}

// ---------------------------------------------------------------------------
// Split-bf16 MFMA GEMM v9 = r8 + XCD-aware block swizzle (T1, adapted).
// Tile 32x32, BK=128 (16 iters), 4 waves, 512 blocks (1-D) -> 2 blocks/CU.
// Swizzle: id -> xcd=id&7, slot=id>>3, bx=xcd*8+(slot&7), by=slot>>3.
// Under %8 round-robin dispatch each XCD touches only bx in [8*xcd, 8*xcd+8):
// B working set 8 panels x 256KB = 2MB + full A 2MB = 4MB = L2-resident.
// Kills the 64x A / 8x B re-fetch from Infinity Cache (r8's ~23us/GEMM wall).
// MODE 0: NN  z=A@Wt; epi: h=tanh(z+b), P=split(h(1-h^2)), csum+=h^2
// MODE 5: NN + folded finalize (block0: done|=max|k1|<TOL, maxu=0)
// MODE 1: NT  kv=-cf*z; epi: S=kv, max|kv|, AB=split(x+0.5DT*kv)
// MODE 2: NT  epi: S+=2kv, AB=split(x+0.5DT*kv)
// MODE 3: NT  epi: S+=2kv, AB=split(x+DT*kv)
// MODE 4: NT  epi: x+=DT/6*(S+kv), AB=split(x_new)
// NT modes zero cs_next (block 0) at kernel end.
// ---------------------------------------------------------------------------
template<int MODE>
__global__ __launch_bounds__(256, 2)
void hop9_mm(const ushort* __restrict__ Ahg, const ushort* __restrict__ Alg,
             const ushort* __restrict__ Bhg, const ushort* __restrict__ Blg,
             const float* __restrict__ bias,
             ushort* __restrict__ Oh, ushort* __restrict__ Ol,
             float* __restrict__ cs_cur, float* __restrict__ cs_next,
             const float* __restrict__ xin, float* __restrict__ xio,
             float* __restrict__ S,
             ushort* __restrict__ Ash, ushort* __restrict__ Asl,
             float cmul, unsigned* __restrict__ maxu, int* __restrict__ done)
{
    constexpr bool NN  = (MODE == 0 || MODE == 5);
    constexpr bool FIN = (MODE == 5);

    if constexpr (FIN) {
        // folded stop-condition update (was finalize_k). Race with other
        // blocks' done-read is benign: once done, their outputs are unused.
        if (blockIdx.x == 0 && threadIdx.x == 0) {
            if (!*done && __uint_as_float(*maxu) < TOL) *done = 1;
            *maxu = 0u;
        }
    }
    if (*done) return;

    // XCD-octant swizzle: each XCD owns a contiguous 8-wide bx band.
    const int id   = blockIdx.x;
    const int xcd  = id & 7, slot = id >> 3;
    const int bx   = xcd * 8 + (slot & 7);      // 0..63 (N tiles)
    const int by   = slot >> 3;                 // 0..7  (M tiles)

    // [dbuf][Ah|Al|Bh|Bl][32 rows][128 k-shorts] = 64 KB
    __shared__ __align__(16) ushort lds[2][16384];

    const int t = threadIdx.x, lane = t & 63, wid = t >> 6;
    const int wr = wid >> 1, wc = wid & 1;
    const int row0 = by * 32, col0 = bx * 32;
    const int fr = lane & 15, cq = lane >> 4;

    // ---- staging: wave wid owns species wid (0=Ah,1=Al,2=Bh,3=Bl) ----
    // per iter: 8 DMA x 1KB per wave (rows 4j..4j+3, 16B chunks 0..15).
    const ushort* sp_src = (wid == 0) ? Ahg : (wid == 1) ? Alg : (wid == 2) ? Bhg : Blg;
    const int sp_base = (wid < 2) ? row0 : col0;
    const int srow4 = lane >> 4, schk = lane & 15;

    auto stage = [&](int it, int db) {
        ushort* L = &lds[db][wid * 4096];
        #pragma unroll
        for (int j = 0; j < 8; ++j) {
            const int r = 4 * j + srow4;
            const ushort* g = sp_src + (size_t)(sp_base + r) * DDIM + it * 128
                              + ((schk ^ (r & 7)) * 8);           // pre-swizzled src
            GLOAD_LDS16(g, L + j * 512 + lane * 8);
        }
    };

    f32x4 acc_e = {0.f, 0.f, 0.f, 0.f};
    f32x4 acc_o = {0.f, 0.f, 0.f, 0.f};

    const int arow = wr * 16 + fr, brow = wc * 16 + fr;
    const int aoffb = arow * 128, boffb = brow * 128;
    const int sa = arow & 7, sb = brow & 7;

    stage(0, 0);
    __syncthreads();

    for (int it = 0; it < 16; ++it) {
        const int db = it & 1;
        if (it < 15) stage(it + 1, db ^ 1);    // prefetch hides under compute
        const ushort* L = &lds[db][0];
        #pragma unroll
        for (int ks = 0; ks < 4; ++ks) {
            const int ca = ((ks * 4 + cq) ^ sa) * 8;
            const int cb = ((ks * 4 + cq) ^ sb) * 8;
            const short8 ah = *(const short8*)&L[        aoffb + ca];
            const short8 al = *(const short8*)&L[ 4096 + aoffb + ca];
            const short8 bh = *(const short8*)&L[ 8192 + boffb + cb];
            const short8 bl = *(const short8*)&L[12288 + boffb + cb];
            if (ks & 1) {
                acc_o = MFMA16(ah, bh, acc_o);
                acc_o = MFMA16(ah, bl, acc_o);
                acc_o = MFMA16(al, bh, acc_o);
            } else {
                acc_e = MFMA16(ah, bh, acc_e);
                acc_e = MFMA16(ah, bl, acc_e);
                acc_e = MFMA16(al, bh, acc_e);
            }
        }
        __syncthreads();
    }

    f32x4 acc;
    #pragma unroll
    for (int j = 0; j < 4; ++j) acc[j] = acc_e[j] + acc_o[j];

    // ---- epilogue. C/D: col=lane&15, row=(lane>>4)*4+j ----
    const int r0 = row0 + wr * 16 + cq * 4;
    const int c0 = col0 + wc * 16 + fr;

    if constexpr (NN) {
        const float b0 = bias[c0];
        float s2[4];
        #pragma unroll
        for (int j = 0; j < 4; ++j) {
            const float h0 = tanhf(acc[j] + b0);
            s2[j] = h0 * h0;
            const float p0 = h0 * (1.f - h0 * h0);
            const size_t i0 = (size_t)(r0 + j) * DDIM + c0;
            const ushort ph = f2bf(p0);
            Oh[i0] = ph; Ol[i0] = f2bf(p0 - bf2f(ph));
        }
        #pragma unroll
        for (int m = 1; m <= 8; m <<= 1)
            #pragma unroll
            for (int j = 0; j < 4; ++j) s2[j] += __shfl_xor(s2[j], m);
        if (fr == 0) {
            #pragma unroll
            for (int j = 0; j < 4; ++j) atomicAdd(&cs_cur[r0 + j], s2[j]);
        }
    } else {
        float mx = 0.f;
        #pragma unroll
        for (int j = 0; j < 4; ++j) {
            const float cf = 5.0f / (sqrtf(cs_cur[r0 + j]) + EPS_);
            const float kv = -cf * acc[j];
            const size_t idx = (size_t)(r0 + j) * DDIM + c0;
            if constexpr (MODE == 1) { S[idx] = kv; mx = fmaxf(mx, fabsf(kv)); }
            if constexpr (MODE == 2 || MODE == 3) { S[idx] += 2.f * kv; }
            if constexpr (MODE <= 3) {
                const float a = xin[idx] + cmul * kv;
                const ushort ahh = f2bf(a);
                Ash[idx] = ahh; Asl[idx] = f2bf(a - bf2f(ahh));
            } else {
                const float xn = xin[idx] + (DT / 6.0f) * (S[idx] + kv);
                xio[idx] = xn;
                const ushort ahh = f2bf(xn);
                Ash[idx] = ahh; Asl[idx] = f2bf(xn - bf2f(ahh));
            }
        }
        if constexpr (MODE == 1) {
            #pragma unroll
            for (int m = 1; m <= 32; m <<= 1) mx = fmaxf(mx, __shfl_xor(mx, m));
            if (lane == 0) atomicMax(maxu, __float_as_uint(mx));
        }
    }

    if (!NN && blockIdx.x == 0) cs_next[t] = 0.f;
}

__global__ __launch_bounds__(256)
void copy_k(const float* __restrict__ src, float* __restrict__ dst)
{
    const size_t i = ((size_t)blockIdx.x * 256 + threadIdx.x) * 4;
    *(float4*)&dst[i] = *(const float4*)&src[i];
}

// ===========================================================================
extern "C" void kernel_launch(void* const* d_in, const int* in_sizes, int n_in,
                              void* d_out, int out_size, void* d_ws, size_t ws_size,
                              hipStream_t stream)
{
    const float* x0   = (const float*)d_in[0];
    const float* W    = (const float*)d_in[1];
    const float* bias = (const float*)d_in[2];
    float* out = (float*)d_out;

    const size_t NE = (size_t)BDIM * DDIM;   // 524288
    const size_t M4 = (size_t)DDIM * DDIM;   // 4194304

    // ws layout (~42 MB; fits the proven >=44.0 MB workspace)
    float* ws = (float*)d_ws;
    float* x    = ws;                        // NE
    float* S    = ws + NE;                   // NE
    float* csum = ws + 2 * NE;               // 1024 (4 stage buffers x 256)
    unsigned* maxu = (unsigned*)(csum + 1024);
    int*      done = (int*)(maxu + 1);
    ushort* us = (ushort*)(ws + 2 * NE + 1032);   // 16B-aligned
    ushort* ABh = us;                // NE: A-side (x + c*k) hi
    ushort* ABl = us + NE;           // NE
    ushort* Ph  = us + 2 * NE;       // NE: p = h(1-h^2) hi
    ushort* Pl  = us + 3 * NE;       // NE
    ushort* Wth = us + 4 * NE;       // M4: W^T hi (NN B)
    ushort* Wtl = Wth + M4;          // M4
    ushort* Wh  = Wth + 2 * M4;      // M4: W hi (NT B)
    ushort* Wl  = Wth + 3 * M4;      // M4

    prep_w_k <<<4096, 256, 0, stream>>>(W, Wh, Wl);
    prep_wt_k<<<dim3(32, 32), 256, 0, stream>>>(W, Wth, Wtl);
    init3_k  <<<512, 256, 0, stream>>>(x0, x, ABh, ABl, csum, maxu, done);

    const int gG = 512;                      // 1-D grid, XCD swizzle in-kernel
    float* cs0 = csum, *cs1 = csum + 256, *cs2 = csum + 512, *cs3 = csum + 768;

    for (int s = 0; s < NSTEP; ++s) {
        // k1 = pvf(x): NN then NT(mode1, sets maxu)
        hop9_mm<0><<<gG, 256, 0, stream>>>(ABh, ABl, Wth, Wtl, bias, Ph, Pl,
                                           cs0, nullptr, nullptr, nullptr, nullptr,
                                           nullptr, nullptr, 0.f, maxu, done);
        hop9_mm<1><<<gG, 256, 0, stream>>>(Ph, Pl, Wh, Wl, nullptr, nullptr, nullptr,
                                           cs0, cs1, x, nullptr, S,
                                           ABh, ABl, 0.5f * DT, maxu, done);
        // k2 (NN carries the folded finalize)
        hop9_mm<5><<<gG, 256, 0, stream>>>(ABh, ABl, Wth, Wtl, bias, Ph, Pl,
                                           cs1, nullptr, nullptr, nullptr, nullptr,
                                           nullptr, nullptr, 0.f, maxu, done);
        hop9_mm<2><<<gG, 256, 0, stream>>>(Ph, Pl, Wh, Wl, nullptr, nullptr, nullptr,
                                           cs1, cs2, x, nullptr, S,
                                           ABh, ABl, 0.5f * DT, maxu, done);
        // k3
        hop9_mm<0><<<gG, 256, 0, stream>>>(ABh, ABl, Wth, Wtl, bias, Ph, Pl,
                                           cs2, nullptr, nullptr, nullptr, nullptr,
                                           nullptr, nullptr, 0.f, maxu, done);
        hop9_mm<3><<<gG, 256, 0, stream>>>(Ph, Pl, Wh, Wl, nullptr, nullptr, nullptr,
                                           cs2, cs3, x, nullptr, S,
                                           ABh, ABl, DT, maxu, done);
        // k4 + RK4 x-update fused
        hop9_mm<0><<<gG, 256, 0, stream>>>(ABh, ABl, Wth, Wtl, bias, Ph, Pl,
                                           cs3, nullptr, nullptr, nullptr, nullptr,
                                           nullptr, nullptr, 0.f, maxu, done);
        hop9_mm<4><<<gG, 256, 0, stream>>>(Ph, Pl, Wh, Wl, nullptr, nullptr, nullptr,
                                           cs3, cs0, x, x, S,
                                           ABh, ABl, 0.f, maxu, done);
    }

    copy_k<<<512, 256, 0, stream>>>(x, out);
}

// Round 10
// 8635.666 us; speedup vs baseline: 11.1969x; 1.2071x over previous
//
#include <hip/hip_runtime.h>
#include <math.h>

#define BDIM 256
#define DDIM 2048
constexpr float DT    = 0.1f;
constexpr float TOL   = 0.01f;
constexpr int   NSTEP = 50;      // int(5.0 / 0.1)
constexpr float EPS_  = 1e-8f;

typedef __attribute__((ext_vector_type(8))) short short8;   // 8 bf16 (MFMA A/B frag)
typedef __attribute__((ext_vector_type(4))) float f32x4;    // MFMA C/D frag

__device__ __forceinline__ ushort f2bf(float f) {           // fp32 -> bf16 RNE
    unsigned u = __float_as_uint(f);
    return (ushort)((u + 0x7fffu + ((u >> 16) & 1u)) >> 16);
}
__device__ __forceinline__ float bf2f(ushort h) { return __uint_as_float(((unsigned)h) << 16); }

#define GLOAD_LDS16(g, l) __builtin_amdgcn_global_load_lds( \
    (const __attribute__((address_space(1))) void*)(g),      \
    (__attribute__((address_space(3))) void*)(l), 16, 0, 0)

#define MFMA16(a, b, c) __builtin_amdgcn_mfma_f32_16x16x32_bf16((a), (b), (c), 0, 0, 0)

// ---------------------------------------------------------------------------
// Shared GEMM core (r9-proven): 32x32 tile, BK=128 (16 iters), 4 waves
// (16x16 quadrant each), dual acc chains, global_load_lds staging with
// XOR swizzle (pre-swizzled source + swizzled read), plain 2-phase loop.
// lds: 32768 ushorts (64 KB). Returns this thread's 4 C values.
// ---------------------------------------------------------------------------
__device__ __forceinline__ f32x4 gemm_core(ushort* lds,
    const ushort* __restrict__ Ahg, const ushort* __restrict__ Alg,
    const ushort* __restrict__ Bhg, const ushort* __restrict__ Blg,
    int row0, int col0)
{
    const int t = threadIdx.x, lane = t & 63, wid = t >> 6;
    const int wr = wid >> 1, wc = wid & 1;
    const int fr = lane & 15, cq = lane >> 4;

    const ushort* sp_src = (wid == 0) ? Ahg : (wid == 1) ? Alg : (wid == 2) ? Bhg : Blg;
    const int sp_base = (wid < 2) ? row0 : col0;
    const int srow4 = lane >> 4, schk = lane & 15;

    auto stage = [&](int it, int db) {
        ushort* L = lds + db * 16384 + wid * 4096;
        #pragma unroll
        for (int j = 0; j < 8; ++j) {
            const int r = 4 * j + srow4;
            const ushort* g = sp_src + (size_t)(sp_base + r) * DDIM + it * 128
                              + ((schk ^ (r & 7)) * 8);           // pre-swizzled src
            GLOAD_LDS16(g, L + j * 512 + lane * 8);
        }
    };

    f32x4 acc_e = {0.f, 0.f, 0.f, 0.f};
    f32x4 acc_o = {0.f, 0.f, 0.f, 0.f};

    const int arow = wr * 16 + fr, brow = wc * 16 + fr;
    const int aoffb = arow * 128, boffb = brow * 128;
    const int sa = arow & 7, sb = brow & 7;

    stage(0, 0);
    __syncthreads();

    for (int it = 0; it < 16; ++it) {
        const int db = it & 1;
        if (it < 15) stage(it + 1, db ^ 1);
        const ushort* L = lds + db * 16384;
        #pragma unroll
        for (int ks = 0; ks < 4; ++ks) {
            const int ca = ((ks * 4 + cq) ^ sa) * 8;
            const int cb = ((ks * 4 + cq) ^ sb) * 8;
            const short8 ah = *(const short8*)&L[        aoffb + ca];
            const short8 al = *(const short8*)&L[ 4096 + aoffb + ca];
            const short8 bh = *(const short8*)&L[ 8192 + boffb + cb];
            const short8 bl = *(const short8*)&L[12288 + boffb + cb];
            if (ks & 1) {
                acc_o = MFMA16(ah, bh, acc_o);
                acc_o = MFMA16(ah, bl, acc_o);
                acc_o = MFMA16(al, bh, acc_o);
            } else {
                acc_e = MFMA16(ah, bh, acc_e);
                acc_e = MFMA16(ah, bl, acc_e);
                acc_e = MFMA16(al, bh, acc_e);
            }
        }
        __syncthreads();
    }

    f32x4 acc;
    #pragma unroll
    for (int j = 0; j < 4; ++j) acc[j] = acc_e[j] + acc_o[j];
    return acc;
}

// ---------------------------------------------------------------------------
// One-time prepacks
// ---------------------------------------------------------------------------
__global__ __launch_bounds__(256)
void prep_w_k(const float* __restrict__ W, ushort* __restrict__ Wh, ushort* __restrict__ Wl)
{
    const size_t i = ((size_t)blockIdx.x * 256 + threadIdx.x) * 4;
    const float4 v = *(const float4*)(W + i);
    ushort4 h, l;
    h.x = f2bf(v.x); l.x = f2bf(v.x - bf2f(h.x));
    h.y = f2bf(v.y); l.y = f2bf(v.y - bf2f(h.y));
    h.z = f2bf(v.z); l.z = f2bf(v.z - bf2f(h.z));
    h.w = f2bf(v.w); l.w = f2bf(v.w - bf2f(h.w));
    *(ushort4*)(Wh + i) = h;
    *(ushort4*)(Wl + i) = l;
}

__global__ __launch_bounds__(256)
void prep_wt_k(const float* __restrict__ W, ushort* __restrict__ Wth, ushort* __restrict__ Wtl)
{
    __shared__ float T[64][65];
    const int t = threadIdx.x;
    const int k0 = blockIdx.y * 64, n0 = blockIdx.x * 64;
    const int r = t >> 2, c4 = (t & 3) * 16;
    const float* src = W + (size_t)(k0 + r) * DDIM + n0 + c4;
    #pragma unroll
    for (int j = 0; j < 4; ++j) {
        const float4 v = *(const float4*)(src + j * 4);
        T[r][c4 + j*4 + 0] = v.x; T[r][c4 + j*4 + 1] = v.y;
        T[r][c4 + j*4 + 2] = v.z; T[r][c4 + j*4 + 3] = v.w;
    }
    __syncthreads();
    ushort hb[16], lb[16];
    #pragma unroll
    for (int j = 0; j < 16; ++j) {
        const float v = T[c4 + j][r];
        hb[j] = f2bf(v); lb[j] = f2bf(v - bf2f(hb[j]));
    }
    ushort* oh = Wth + (size_t)(n0 + r) * DDIM + k0 + c4;
    ushort* ol = Wtl + (size_t)(n0 + r) * DDIM + k0 + c4;
    #pragma unroll
    for (int q = 0; q < 4; ++q) {
        *(ushort4*)(oh + q*4) = make_ushort4(hb[q*4], hb[q*4+1], hb[q*4+2], hb[q*4+3]);
        *(ushort4*)(ol + q*4) = make_ushort4(lb[q*4], lb[q*4+1], lb[q*4+2], lb[q*4+3]);
    }
}

// init: bufB = split(x0); zero Utot, csum, maxu, done
__global__ __launch_bounds__(256)
void init10_k(const float* __restrict__ x0,
              ushort* __restrict__ Bh, ushort* __restrict__ Bl,
              float* __restrict__ Utot, float* __restrict__ csum,
              unsigned* __restrict__ maxu, int* __restrict__ done)
{
    const size_t i = ((size_t)blockIdx.x * 256 + threadIdx.x) * 4;
    const float4 v = *(const float4*)(x0 + i);
    ushort4 h, l;
    h.x = f2bf(v.x); l.x = f2bf(v.x - bf2f(h.x));
    h.y = f2bf(v.y); l.y = f2bf(v.y - bf2f(h.y));
    h.z = f2bf(v.z); l.z = f2bf(v.z - bf2f(h.z));
    h.w = f2bf(v.w); l.w = f2bf(v.w - bf2f(h.w));
    *(ushort4*)(Bh + i) = h;
    *(ushort4*)(Bl + i) = l;
    *(float4*)(Utot + i) = make_float4(0.f, 0.f, 0.f, 0.f);
    if (blockIdx.x == 0) {
        for (int j = threadIdx.x; j < 1024; j += 256) csum[j] = 0.f;
        if (threadIdx.x == 0) { *maxu = 0u; *done = 0; }
    }
}

// ---------------------------------------------------------------------------
// G = Wt @ Wt^T = W^T W, split-bf16 output. Grid 4096 (64x64 tiles of 32x32).
// ---------------------------------------------------------------------------
__global__ __launch_bounds__(256, 2)
void gbuild_mm(const ushort* __restrict__ Wth, const ushort* __restrict__ Wtl,
               ushort* __restrict__ Gh, ushort* __restrict__ Gl)
{
    __shared__ __align__(16) ushort lds[32768];
    const int id = blockIdx.x;
    const int bx = id & 63, by = id >> 6;
    const f32x4 acc = gemm_core(lds, Wth, Wtl, Wth, Wtl, by * 32, bx * 32);

    const int lane = threadIdx.x & 63, wid = threadIdx.x >> 6;
    const int r0 = by * 32 + (wid >> 1) * 16 + (lane >> 4) * 4;
    const int c0 = bx * 32 + (wid & 1) * 16 + (lane & 15);
    #pragma unroll
    for (int j = 0; j < 4; ++j) {
        const size_t idx = (size_t)(r0 + j) * DDIM + c0;
        const ushort gh = f2bf(acc[j]);
        Gh[idx] = gh; Gl[idx] = f2bf(acc[j] - bf2f(gh));
    }
}

// ---------------------------------------------------------------------------
// z-space pipeline kernel. Grid 512 (1-D, XCD swizzle), 2 blocks/CU.
// MODE 0 Z0:   z = x0@Wt + b; produce P1=split(u1); cs_out += h^2
// MODE 1 Z1:   kz=-cf*acc; S=kz;   zs=z+c*kz; w-accum(prev w4); produce P
// MODE 2 ZMID: kz=-cf*acc; S+=2kz; zs=z+c*kz; w-accum;          produce P
// MODE 4 Z4:   kz=-cf*acc; z+=DT/6*(S+kz);    w-accum;          produce P
// MODE 5 STOP: atomicMax(maxu, cf*|acc|) only (no stores)
// MODE 6 FINAL: out = x0 - acc  (A operand = split(Utot); runs even if done)
// w-accum: Utot[idx] += w_acc * cf(cs_acc) * (bf2f(oPh)+bf2f(oPl)) BEFORE
// overwriting oP with the newly produced u (same thread, same idx).
// Each Z mode zeroes one csum buffer (block 0) for a later stage.
// ---------------------------------------------------------------------------
template<int MODE>
__global__ __launch_bounds__(256, 2)
void hop10_mm(const ushort* __restrict__ Ahg, const ushort* __restrict__ Alg,
              const ushort* __restrict__ Bhg, const ushort* __restrict__ Blg,
              const float* __restrict__ bias,
              float* __restrict__ z, float* __restrict__ S, float* __restrict__ Utot,
              const float* __restrict__ cs_cf, const float* __restrict__ cs_acc,
              float* __restrict__ cs_out, float* __restrict__ cs_zero,
              ushort* oPh, ushort* oPl,
              float w_acc, float cstage,
              const float* __restrict__ x0, float* __restrict__ outb,
              unsigned* __restrict__ maxu, const int* __restrict__ done)
{
    if constexpr (MODE >= 1 && MODE <= 5) {
        if (*done) return;
    }

    __shared__ __align__(16) ushort lds[32768];

    // XCD-octant swizzle (kept from r9; neutral-to-positive)
    const int id  = blockIdx.x;
    const int bx  = (id & 7) * 8 + ((id >> 3) & 7);   // 0..63
    const int by  = id >> 6;                          // 0..7

    const f32x4 acc = gemm_core(lds, Ahg, Alg, Bhg, Blg, by * 32, bx * 32);

    const int t = threadIdx.x, lane = t & 63, wid = t >> 6;
    const int fr = lane & 15;
    const int r0 = by * 32 + (wid >> 1) * 16 + (lane >> 4) * 4;
    const int c0 = bx * 32 + (wid & 1) * 16 + fr;

    if constexpr (MODE == 6) {                    // FINAL: out = x0 - Utot@W^T
        #pragma unroll
        for (int j = 0; j < 4; ++j) {
            const size_t idx = (size_t)(r0 + j) * DDIM + c0;
            outb[idx] = x0[idx] - acc[j];
        }
        return;
    }

    if constexpr (MODE == 5) {                    // STOP: max|kx1|
        float mx = 0.f;
        #pragma unroll
        for (int j = 0; j < 4; ++j) {
            const float cf = 5.0f / (sqrtf(cs_cf[r0 + j]) + EPS_);
            mx = fmaxf(mx, cf * fabsf(acc[j]));
        }
        #pragma unroll
        for (int m = 1; m <= 32; m <<= 1) mx = fmaxf(mx, __shfl_xor(mx, m));
        if (lane == 0) atomicMax(maxu, __float_as_uint(mx));
        return;
    }

    // Z modes: produce u for the next stage + bookkeeping
    float s2[4];
    #pragma unroll
    for (int j = 0; j < 4; ++j) {
        const int row = r0 + j;
        const size_t idx = (size_t)row * DDIM + c0;
        float zs;
        if constexpr (MODE == 0) {
            zs = acc[j] + bias[c0];
            z[idx] = zs;
        } else {
            const float cf = 5.0f / (sqrtf(cs_cf[row]) + EPS_);
            const float kz = -cf * acc[j];
            if constexpr (MODE == 1) { S[idx] = kz; zs = z[idx] + cstage * kz; }
            if constexpr (MODE == 2) { S[idx] += 2.f * kz; zs = z[idx] + cstage * kz; }
            if constexpr (MODE == 4) { zs = z[idx] + (DT / 6.0f) * (S[idx] + kz); z[idx] = zs; }
            if (w_acc != 0.f) {       // accumulate previous stage's Utot term
                const float ua  = bf2f(oPh[idx]) + bf2f(oPl[idx]);
                const float cfa = 5.0f / (sqrtf(cs_acc[row]) + EPS_);
                Utot[idx] += w_acc * cfa * ua;
            }
        }
        const float h = tanhf(zs);
        s2[j] = h * h;
        const float u = h * (1.f - h * h);
        const ushort uh = f2bf(u);
        oPh[idx] = uh; oPl[idx] = f2bf(u - bf2f(uh));
    }
    #pragma unroll
    for (int m = 1; m <= 8; m <<= 1)
        #pragma unroll
        for (int j = 0; j < 4; ++j) s2[j] += __shfl_xor(s2[j], m);
    if (fr == 0) {
        #pragma unroll
        for (int j = 0; j < 4; ++j) atomicAdd(&cs_out[r0 + j], s2[j]);
    }

    if (cs_zero && blockIdx.x == 0) cs_zero[t] = 0.f;
}

__global__ void finalize_k(unsigned* __restrict__ maxu, int* __restrict__ done)
{
    if (!*done) {
        if (__uint_as_float(*maxu) < TOL) *done = 1;
    }
    *maxu = 0u;
}

// tail: Utot += (DT/6)*cf4*u4 (iff !done), then bufB <- split(Utot)
__global__ __launch_bounds__(256)
void tailsplit_k(float* __restrict__ Utot, const float* __restrict__ cs4,
                 ushort* bh, ushort* bl, const int* __restrict__ done)
{
    const size_t base = ((size_t)blockIdx.x * 256 + threadIdx.x) * 4;
    const int row = (int)(base >> 11);
    const int add = !(*done);
    float4 u = *(const float4*)(Utot + base);
    if (add) {
        const float cfa = (DT / 6.0f) * 5.0f / (sqrtf(cs4[row]) + EPS_);
        const ushort4 ph = *(const ushort4*)(bh + base);
        const ushort4 pl = *(const ushort4*)(bl + base);
        u.x += cfa * (bf2f(ph.x) + bf2f(pl.x));
        u.y += cfa * (bf2f(ph.y) + bf2f(pl.y));
        u.z += cfa * (bf2f(ph.z) + bf2f(pl.z));
        u.w += cfa * (bf2f(ph.w) + bf2f(pl.w));
    }
    ushort4 h, l;
    h.x = f2bf(u.x); l.x = f2bf(u.x - bf2f(h.x));
    h.y = f2bf(u.y); l.y = f2bf(u.y - bf2f(h.y));
    h.z = f2bf(u.z); l.z = f2bf(u.z - bf2f(h.z));
    h.w = f2bf(u.w); l.w = f2bf(u.w - bf2f(h.w));
    *(ushort4*)(bh + base) = h;
    *(ushort4*)(bl + base) = l;
}

// ===========================================================================
extern "C" void kernel_launch(void* const* d_in, const int* in_sizes, int n_in,
                              void* d_out, int out_size, void* d_ws, size_t ws_size,
                              hipStream_t stream)
{
    const float* x0   = (const float*)d_in[0];
    const float* W    = (const float*)d_in[1];
    const float* bias = (const float*)d_in[2];
    float* out = (float*)d_out;

    const size_t NE = (size_t)BDIM * DDIM;   // 524288
    const size_t M4 = (size_t)DDIM * DDIM;   // 4194304

    // ws layout: 44,044,320 B <= 44,048,384 B proven (r2 gate ran MFMA path)
    float* ws = (float*)d_ws;
    float* z    = ws;                        // NE
    float* S    = ws + NE;                   // NE
    float* Utot = ws + 2 * NE;               // NE
    float* csum = ws + 3 * NE;               // 1024 (4 stage buffers x 256)
    unsigned* maxu = (unsigned*)(csum + 1024);
    int*      done = (int*)(maxu + 1);
    ushort* us = (ushort*)(ws + 3 * NE + 1032);   // 16B-aligned
    ushort* bAh = us;                // ping buffer A (P hi)
    ushort* bAl = us + NE;           //               (P lo)
    ushort* bBh = us + 2 * NE;       // pong buffer B
    ushort* bBl = us + 3 * NE;
    ushort* Gh  = us + 4 * NE;       // M4: G = W^T W hi
    ushort* Gl  = Gh + M4;           // M4
    ushort* Wxh = Gl + M4;           // M4: Wt (setup) then W (runtime) hi
    ushort* Wxl = Wxh + M4;          // M4

    float* cs1 = csum, *cs2 = csum + 256, *cs3 = csum + 512, *cs4 = csum + 768;
    constexpr float W16 = DT / 6.0f, W13 = DT / 3.0f;

    // ---- setup ----
    prep_wt_k<<<dim3(32, 32), 256, 0, stream>>>(W, Wxh, Wxl);          // R_W <- Wt
    init10_k <<<512, 256, 0, stream>>>(x0, bBh, bBl, Utot, csum, maxu, done);
    // z0 = x0@Wt + b; produce P1 -> bufA; csum1 += h^2
    hop10_mm<0><<<512, 256, 0, stream>>>(bBh, bBl, Wxh, Wxl, bias,
                                         z, S, Utot, nullptr, nullptr, cs1, nullptr,
                                         bAh, bAl, 0.f, 0.f, nullptr, nullptr, maxu, done);
    gbuild_mm<<<4096, 256, 0, stream>>>(Wxh, Wxl, Gh, Gl);             // G <- Wt@Wt^T
    prep_w_k <<<4096, 256, 0, stream>>>(W, Wxh, Wxl);                  // R_W <- W

    // ---- 50 RK4 steps in z-space ----
    for (int s = 0; s < NSTEP; ++s) {
        // Z1: in=A, out=B (w4-accum of prev step), cf=cs1, acc=cs4, cs_out=cs2, zero=cs3
        hop10_mm<1><<<512, 256, 0, stream>>>(bAh, bAl, Gh, Gl, nullptr,
                                             z, S, Utot, cs1, cs4, cs2, cs3,
                                             bBh, bBl, (s == 0) ? 0.f : W16, 0.5f * DT,
                                             nullptr, nullptr, maxu, done);
        // STOP: kx1 max (in=A, B=W)
        hop10_mm<5><<<512, 256, 0, stream>>>(bAh, bAl, Wxh, Wxl, nullptr,
                                             z, S, Utot, cs1, nullptr, nullptr, nullptr,
                                             nullptr, nullptr, 0.f, 0.f,
                                             nullptr, nullptr, maxu, done);
        finalize_k<<<1, 1, 0, stream>>>(maxu, done);
        // Z2: in=B, out=A (w1-accum), cf=cs2, acc=cs1, cs_out=cs3, zero=cs4
        hop10_mm<2><<<512, 256, 0, stream>>>(bBh, bBl, Gh, Gl, nullptr,
                                             z, S, Utot, cs2, cs1, cs3, cs4,
                                             bAh, bAl, W16, 0.5f * DT,
                                             nullptr, nullptr, maxu, done);
        // Z3: in=A, out=B (w2-accum), cf=cs3, acc=cs2, cs_out=cs4, zero=cs1
        hop10_mm<2><<<512, 256, 0, stream>>>(bAh, bAl, Gh, Gl, nullptr,
                                             z, S, Utot, cs3, cs2, cs4, cs1,
                                             bBh, bBl, W13, DT,
                                             nullptr, nullptr, maxu, done);
        // Z4: in=B, out=A (w3-accum), cf=cs4, acc=cs3, cs_out=cs1, zero=cs2
        hop10_mm<4><<<512, 256, 0, stream>>>(bBh, bBl, Gh, Gl, nullptr,
                                             z, S, Utot, cs4, cs3, cs1, cs2,
                                             bAh, bAl, W13, 0.f,
                                             nullptr, nullptr, maxu, done);
    }

    // ---- tail: pending w4-term (iff !done), split Utot, final x recovery ----
    tailsplit_k<<<512, 256, 0, stream>>>(Utot, cs4, bBh, bBl, done);
    hop10_mm<6><<<512, 256, 0, stream>>>(bBh, bBl, Wxh, Wxl, nullptr,
                                         z, S, Utot, nullptr, nullptr, nullptr, nullptr,
                                         nullptr, nullptr, 0.f, 0.f,
                                         x0, out, maxu, done);
}